// Round 4
// baseline (521.765 us; speedup 1.0000x reference)
//
#include <hip/hip_runtime.h>

#define N_ 2000
#define L_ 1024

__device__ __forceinline__ float rcpf(float d) { return __builtin_amdgcn_rcpf(d); }
__device__ __forceinline__ float ex2(float x)  { return __builtin_amdgcn_exp2f(x); }

// One FULL chain per lane; chain-minimized step.
// Serial path: m -> valm -> G -> rcp -> Vn -> ex2 -> rcp -> s -> q -> rcp -> m'
// (h,y updates + E/numerator/output all scheduled off the critical path).
// Ring-16 z prefetch: at step K consume z[K-1] (slot (K-1)&15), load z[K+15].
#define STEP1(K, RS)                                                          \
  {                                                                           \
    const int kk = (K);                                                       \
    float zc = zb[RS];                                                        \
    int kpre = kk + 15;                                                       \
    int kc = kpre < 1998 ? kpre : 1998;                                       \
    zb[RS] = z[base + kc * L_];                                               \
    /* G,E trees (balanced; valm via parallel muls) */                        \
    float mh   = m * h;                                                       \
    float m2   = m * m;                                                       \
    float valm = m2 * mh;              /* m^3 h */                            \
    float n2   = n * n;                                                       \
    float valn = n2 * n2;              /* n^4  */                             \
    float gy   = __fmaf_rn(y, 0.01f, 0.003f);                                 \
    float G    = __fmaf_rn(valm, 0.4f, __fmaf_rn(valn, 0.35f, gy));           \
    float E    = __fmaf_rn(valm, 2200.0f, __fmaf_rn(valn, -2695.0f, -19.5f)); \
    /* Vn = (2V + DT(E+1))*r - V,  r = 1/(1+G): numerator off-chain */        \
    float r    = rcpf(1.0f + G);                                              \
    float tVD  = __fmaf_rn(E, 0.02f, __fmaf_rn(2.0f, V, 0.02f));              \
    float Vn   = __fmaf_rn(tVD, r, -V);                                       \
    /* m,n rates */                                                           \
    float eRm  = ex2(__fmaf_rn(Vn, K9, 35.0f * K9));                          \
    float eRn  = ex2(__fmaf_rn(Vn, K9, -25.0f * K9));                         \
    float rrm  = rcpf(eRm - 1.0f);                                            \
    float rrn  = rcpf(eRn - 1.0f);                                            \
    float um   = Vn + 35.0f;                                                  \
    float un   = Vn - 25.0f;                                                  \
    float urm  = um * rrm;                                                    \
    float urn  = un * rrn;                                                    \
    float Xm   = __fmaf_rn(0.00182f, eRm, 0.00124f);                          \
    float Xn   = __fmaf_rn(0.0002f,  eRn, 0.00002f);                          \
    float sm   = urm * Xm;                                                    \
    float sn   = urn * Xn;                                                    \
    float aM   = 0.182f * (urm * eRm);                                        \
    float aN   = 0.02f  * (urn * eRn);                                        \
    bool patm  = (Vn == -35.0f);                                              \
    bool patn  = (Vn == 25.0f);                                               \
    sm = patm ? 0.02798f : sm;  aM = patm ? 1.638f : aM;                      \
    sn = patn ? 0.0026f  : sn;  aN = patn ? 0.18f  : aN;                      \
    /* m,n gate updates: own rcp (shortest chain back into valm/valn) */      \
    float numm = __fmaf_rn(aM, 0.02f, __fmaf_rn(-sm, m, m));                  \
    float numn = __fmaf_rn(aN, 0.02f, __fmaf_rn(-sn, n, n));                  \
    m = numm * rcpf(1.0f + sm);                                               \
    n = numn * rcpf(1.0f + sn);                                               \
    /* h,y updates: off critical path, paired rcp */                          \
    float aH   = 0.25f * ex2(__fmaf_rn(Vn, -K12, -90.0f * K12));              \
    float bH   = 0.25f * ex2(__fmaf_rn(Vn,  K12,  34.0f * K12));              \
    float sh   = __fmaf_rn(aH, 0.01f, 0.01f * bH);                            \
    float numh = __fmaf_rn(aH, 0.02f, __fmaf_rn(-sh, h, h));                  \
    float qh   = 1.0f + sh;                                                   \
    float sy   = __fmaf_rn(zc, 0.01f, 0.001f);                                \
    float numy = __fmaf_rn(zc, 0.02f, __fmaf_rn(-sy, y, y));                  \
    float qy   = 1.0f + sy;                                                   \
    float rq   = rcpf(qh * qy);                                               \
    h = numh * (rq * qy);                                                     \
    y = numy * (rq * qh);                                                     \
    V = Vn;                                                                   \
    /* out: sigmoid((Vn+20)/3) = t/(1+t), t = eRm^3 * e^-5 */                 \
    float e2 = eRm * eRm;                                                     \
    float ts = (e2 * eRm) * 0.006737946999085467f;                            \
    float sg = ts * rcpf(1.0f + ts);                                          \
    __builtin_nontemporal_store(sg, &out[base + kk * L_]);                    \
  }

__global__ __launch_bounds__(64) void hh_kernel(const float* __restrict__ z,
                                                float* __restrict__ out) {
    const int t   = blockIdx.x * 64 + threadIdx.x;   // chain 0..16383
    const int b   = t >> 10;
    const int l   = t & 1023;
    const int base = b * (N_ * L_) + l;

    const float K9  = 0.16029944898766259f;   // log2(e)/9
    const float K12 = 0.12022458674074695f;   // log2(e)/12

    float V = -70.0f;
    float m = 0.0f, n = 0.0f, h = 1.0f, y = 0.0f;

    float zb[16];
#pragma unroll
    for (int i = 0; i < 16; ++i) zb[i] = z[base + i * L_];

    // row 0: sigmoid((-70+20)/3), constant
    __builtin_nontemporal_store(5.777750e-8f, &out[base]);

    int k = 1;
    for (int g = 0; g < 124; ++g) {          // K = 1 .. 1984
#pragma unroll
        for (int j = 0; j < 16; ++j) {
            STEP1(k + j, j)
        }
        k += 16;
    }
    // K = 1985 .. 1999 (slots 0..14)
#pragma unroll
    for (int j = 0; j < 15; ++j) {
        STEP1(k + j, j)
    }
}

extern "C" void kernel_launch(void* const* d_in, const int* in_sizes, int n_in,
                              void* d_out, int out_size, void* d_ws, size_t ws_size,
                              hipStream_t stream) {
    const float* z = (const float*)d_in[0];
    float* out = (float*)d_out;
    // 16384 chains x 1 lane = 16384 threads = 256 waves (1 per CU)
    hh_kernel<<<256, 64, 0, stream>>>(z, out);
}